// Round 15
// baseline (104.429 us; speedup 1.0000x reference)
//
#include <hip/hip_runtime.h>
#include <hip/hip_bf16.h>

#define BATCH 262144
#define NSITES 64
#define NJ 4                    // j-tiles per wave (64 batch elems/wave)
#define BLOCK_BATCH 256         // batch elems per 256-thread block

typedef __attribute__((ext_vector_type(8))) short short8;
typedef __attribute__((ext_vector_type(4))) float f32x4;

// slot k = [k4 k3 | k2 k1 k0] -> logical chi = 16*k2 + 4*(k4k3) + (k1k0)
__device__ __forceinline__ int qmap(int k) {
  return (((k >> 2) & 1) << 4) | (((k >> 3) & 3) << 2) | (k & 3);
}

// pack: element idx = ((p*4 + f)*64 + l)*8 + t   (chunk = 16B = 8 bf16)
// f = m*2 + h ; l = g*16 + col ; value = bf16(cores[p][qmap(8g+t)][m][h*16+col] - delta)
// step s (1..63) reads panel p = s-1 at byte offset p*4096 + f*1024 + l*16.
__global__ void pack_E(const float* __restrict__ cores, unsigned short* __restrict__ Ep) {
  int idx = blockIdx.x * 256 + threadIdx.x;
  if (idx >= (NSITES - 1) * 2048) return;
  int t = idx & 7;
  int l = (idx >> 3) & 63;
  int f = (idx >> 9) & 3;
  int p = idx >> 11;
  int g = l >> 4, col = l & 15;
  int m = f >> 1, h = f & 1;
  int k = 8 * g + t, c = h * 16 + col;
  int b = qmap(k);
  float val = cores[((p * 32 + b) * 2 + m) * 32 + c] - ((b == c) ? 1.0f : 0.0f);
  __hip_bfloat16 hv = __float2bfloat16(val);
  Ep[idx] = *(unsigned short*)&hv;
}

__device__ __forceinline__ void gll16(const void* g, void* l) {
  __builtin_amdgcn_global_load_lds(
      (const __attribute__((address_space(1))) unsigned*)g,
      (__attribute__((address_space(3))) unsigned*)l, 16, 0, 0);
}
__device__ __forceinline__ void gll4(const void* g, void* l) {
  __builtin_amdgcn_global_load_lds(
      (const __attribute__((address_space(1))) unsigned*)g,
      (__attribute__((address_space(3))) unsigned*)l, 4, 0, 0);
}

#define BODYJ(jj, xx0, xx1)                                                     \
  {                                                                             \
    union { short8 s8; __hip_bfloat162 h2[4]; } vb;                             \
    vb.h2[0] = __float22bfloat162_rn(make_float2(v[jj][0], v[jj][1]));          \
    vb.h2[1] = __float22bfloat162_rn(make_float2(v[jj][2], v[jj][3]));          \
    vb.h2[2] = __float22bfloat162_rn(make_float2(v[jj][4], v[jj][5]));          \
    vb.h2[3] = __float22bfloat162_rn(make_float2(v[jj][6], v[jj][7]));          \
    const f32x4 z = {0.f, 0.f, 0.f, 0.f};                                       \
    __builtin_amdgcn_s_setprio(1);                                              \
    f32x4 r0lo = __builtin_amdgcn_mfma_f32_16x16x32_bf16(A0, vb.s8, z, 0, 0, 0); \
    f32x4 r0hi = __builtin_amdgcn_mfma_f32_16x16x32_bf16(A1, vb.s8, z, 0, 0, 0); \
    f32x4 r1lo = __builtin_amdgcn_mfma_f32_16x16x32_bf16(A2, vb.s8, z, 0, 0, 0); \
    f32x4 r1hi = __builtin_amdgcn_mfma_f32_16x16x32_bf16(A3, vb.s8, z, 0, 0, 0); \
    __builtin_amdgcn_s_setprio(0);                                              \
    const float ss = (xx0) + (xx1);                                             \
    _Pragma("unroll") for (int t = 0; t < 4; ++t) {                             \
      v[jj][t] = ss * v[jj][t] + (xx0)*r0lo[t] + (xx1)*r1lo[t];                 \
      v[jj][4 + t] = ss * v[jj][4 + t] + (xx0)*r0hi[t] + (xx1)*r1hi[t];         \
    }                                                                           \
  }

__global__ __launch_bounds__(256, 4) void mps_chain_kernel(
    const float* __restrict__ X, const float* __restrict__ core0,
    const float* __restrict__ coreN, const unsigned short* __restrict__ Ep,
    float* __restrict__ out) {
  // wave-private double buffer: [wave][buf] = 4KB E panel + 256B x0 + 256B x1
  __shared__ __align__(16) char Lds[4][2][4608];
  const int tid = threadIdx.x;
  const int lane = tid & 63;
  const int wave = tid >> 6;
  const int col = lane & 15;  // batch column within 16-wide tile
  const int g = lane >> 4;    // k-group (slots 8g..8g+7)
  const int abase = blockIdx.x * BLOCK_BATCH + wave * (16 * NJ);
  const char* Epc = (const char*)Ep;
  const char* Xc = (const char*)X;

  // stage E(panel t-1) + X(t) for step t into wave-private buf b. 6 VMEM ops.
#define STAGE(t_, b_)                                                           \
  {                                                                             \
    const char* es_ = Epc + (size_t)((t_)-1) * 4096 + (size_t)lane * 16;        \
    gll16(es_, &Lds[wave][b_][0]);                                              \
    gll16(es_ + 1024, &Lds[wave][b_][1024]);                                    \
    gll16(es_ + 2048, &Lds[wave][b_][2048]);                                    \
    gll16(es_ + 3072, &Lds[wave][b_][3072]);                                    \
    const char* xs_ = Xc + ((size_t)(t_)*BATCH + abase + lane) * 8;             \
    gll4(xs_, &Lds[wave][b_][4096]);                                            \
    gll4(xs_ + 4, &Lds[wave][b_][4352]);                                        \
  }

  // ---- v0 = X[0] @ core0 (plain one-time loads) ----
  float c0[2][8];
#pragma unroll
  for (int m = 0; m < 2; ++m)
#pragma unroll
    for (int t = 0; t < 8; ++t) c0[m][t] = core0[m * 32 + qmap(8 * g + t)];

  float v[NJ][8];
#pragma unroll
  for (int jj = 0; jj < NJ; ++jj) {
    const float2 xj = *(const float2*)(X + 2 * (size_t)(abase + jj * 16 + col));
#pragma unroll
    for (int t = 0; t < 8; ++t) v[jj][t] = xj.x * c0[0][t] + xj.y * c0[1][t];
  }

  // ---- prologue: stage step 1 into buf 1 ----
  STAGE(1, 1);

  // ---- main chain: wave-private dbuf, counted vmcnt, NO barriers ----
  // Entering step s: <=6 outstanding = stage(s), issued one full step ago.
#pragma unroll 1
  for (int s = 1; s < NSITES; ++s) {
    const int rb = s & 1;
    if (s + 1 < NSITES) {
      STAGE(s + 1, rb ^ 1);  // 12 in flight
      asm volatile("s_waitcnt vmcnt(6)" ::: "memory");  // drains stage(s)
    } else {
      asm volatile("s_waitcnt vmcnt(0)" ::: "memory");
    }

    const short8* ep = (const short8*)&Lds[wave][rb][lane * 16];
    const short8 A0 = ep[0], A1 = ep[64], A2 = ep[128], A3 = ep[192];
    const float* xp = (const float*)&Lds[wave][rb][4096];
    float xv0[NJ], xv1[NJ];
#pragma unroll
    for (int jj = 0; jj < NJ; ++jj) {
      xv0[jj] = xp[jj * 16 + col];
      xv1[jj] = xp[64 + jj * 16 + col];
    }

    BODYJ(0, xv0[0], xv1[0]);
    BODYJ(1, xv0[1], xv1[1]);
    BODYJ(2, xv0[2], xv1[2]);
    BODYJ(3, xv0[3], xv1[3]);
  }

  // ---- epilogue: out = |v @ coreN| ----
  float cN[8][2];
#pragma unroll
  for (int t = 0; t < 8; ++t) {
    cN[t][0] = coreN[qmap(8 * g + t) * 2 + 0];
    cN[t][1] = coreN[qmap(8 * g + t) * 2 + 1];
  }
#pragma unroll
  for (int jj = 0; jj < NJ; ++jj) {
    float p0 = 0.f, p1 = 0.f;
#pragma unroll
    for (int t = 0; t < 8; ++t) {
      p0 += v[jj][t] * cN[t][0];
      p1 += v[jj][t] * cN[t][1];
    }
    p0 += __shfl_xor(p0, 16);
    p0 += __shfl_xor(p0, 32);
    p1 += __shfl_xor(p1, 16);
    p1 += __shfl_xor(p1, 32);
    if (g == 0) {
      const int a = abase + jj * 16 + col;
      out[2 * a] = fabsf(p0);
      out[2 * a + 1] = fabsf(p1);
    }
  }
#undef STAGE
}

extern "C" void kernel_launch(void* const* d_in, const int* in_sizes, int n_in,
                              void* d_out, int out_size, void* d_ws, size_t ws_size,
                              hipStream_t stream) {
  const float* X = (const float*)d_in[0];
  const float* core0 = (const float*)d_in[1];
  const float* cores = (const float*)d_in[2];
  const float* coreN = (const float*)d_in[3];
  float* out = (float*)d_out;
  unsigned short* Ep = (unsigned short*)d_ws;  // 258048 bytes

  hipLaunchKernelGGL(pack_E, dim3(((NSITES - 1) * 2048 + 255) / 256), dim3(256), 0, stream,
                     cores, Ep);
  hipLaunchKernelGGL(mps_chain_kernel, dim3(BATCH / BLOCK_BATCH), dim3(256), 0, stream, X,
                     core0, coreN, Ep, out);
}